// Round 2
// baseline (1507.036 us; speedup 1.0000x reference)
//
#include <hip/hip_runtime.h>
#include <math.h>

// ---------------- problem constants ----------------
constexpr int B_  = 2048;
constexpr int S_  = 5;
constexpr int N_  = 80;
constexpr int E_  = 592;
constexpr int FX_ = 8;
constexpr int FF_ = 4;
constexpr int FE_ = 8;
constexpr int D_  = 8;
constexpr int H_  = 800;

constexpr int BS_  = B_ * S_;         // 10240 graphs
constexpr int XD_  = N_ * D_;         // 640
constexpr int ED_  = E_ * D_;         // 4736
constexpr int SEQ_ = XD_ + ED_;       // 5376 (GRU input width)
constexpr int G3_  = 3 * H_;          // 2400
constexpr int MIN_ = S_ * H_;         // 4000 (mlp input width)
constexpr int MH_  = 1280;            // mlp hidden
constexpr int MO_  = S_ * 80;         // 400 (mlp output width)

typedef __bf16 bf16_t;
typedef __bf16 bf16x8 __attribute__((ext_vector_type(8)));
typedef float  f32x4  __attribute__((ext_vector_type(4)));

__device__ __forceinline__ float sigmoidf_(float x) {
    return 1.0f / (1.0f + expf(-x));
}

// async global->LDS, 16 bytes per lane (global_load_lds_dwordx4)
__device__ __forceinline__ void async16(const void* g, void* l) {
    __builtin_amdgcn_global_load_lds(
        (const __attribute__((address_space(1))) unsigned int*)g,
        (__attribute__((address_space(3))) unsigned int*)l,
        16, 0, 0);
}

// ---------------- GNN: one WAVE per (b,s) graph, 4 graphs per block ----------
__global__ __launch_bounds__(256, 4) void gnn_kernel(
    const float* __restrict__ x,      // [BS, N, FX]
    const int*   __restrict__ ei,     // [BS, 2, E]
    const float* __restrict__ ef,     // [BS, E, FF]
    const float* __restrict__ ea,     // [BS, E, FE]
    const float* __restrict__ Wx,     // [FX, D]
    const float* __restrict__ We,     // [FE, D]
    const float* __restrict__ Wf,     // [FF, D]
    const float* __restrict__ Wedge,  // [2D+FE=24, D]
    bf16_t* __restrict__ seq)         // [BS, SEQ] bf16
{
    const int tid  = threadIdx.x;
    const int w    = tid >> 6;
    const int lane = tid & 63;
    const int g    = blockIdx.x * 4 + w;

    __shared__ float sWx[FX_ * D_];      // 64
    __shared__ float sWe[FE_ * D_];      // 64
    __shared__ float sWf[FF_ * D_];      // 32
    __shared__ float sWedge[24 * D_];    // 192
    __shared__ float agg[4][D_ * N_];    // [wave][d*80+n]  2.5KB/wave
    __shared__ float su [4][D_ * N_];    // u = xout @ Wedge[0:8]
    __shared__ float sv [4][D_ * N_];    // v = xout @ Wedge[8:16]

    if (tid < 64) { sWx[tid] = Wx[tid]; sWe[tid] = We[tid]; }
    if (tid < 32) sWf[tid] = Wf[tid];
    if (tid < 192) sWedge[tid] = Wedge[tid];

    float* aggw = agg[w];
    float* uw   = su[w];
    float* vw   = sv[w];
    for (int i = lane; i < D_ * N_; i += 64) aggw[i] = 0.0f;

    const int* srcp = ei + (size_t)g * 2 * E_;
    const int* dstp = srcp + E_;

    // wave-local min of src (reference: min over edge_index[...,0,:])
    int lmin = 0x7fffffff;
    for (int e = lane; e < E_; e += 64) lmin = min(lmin, srcp[e]);
    #pragma unroll
    for (int off = 32; off; off >>= 1)
        lmin = min(lmin, __shfl_xor(lmin, off, 64));
    const int mn = lmin;

    __syncthreads();   // weights + agg-zero visible

    // ---- phase 1: edge messages, scatter-add into agg[d][n] ----
    const float* eag = ea + (size_t)g * E_ * FE_;
    const float* efg = ef + (size_t)g * E_ * FF_;
    for (int e = lane; e < E_; e += 64) {
        const float4* ap = (const float4*)(eag + (size_t)e * FE_);
        float4 a0 = ap[0], a1 = ap[1];
        float4 f0 = *(const float4*)(efg + (size_t)e * FF_);
        float a[FE_] = {a0.x, a0.y, a0.z, a0.w, a1.x, a1.y, a1.z, a1.w};
        float fv[FF_] = {f0.x, f0.y, f0.z, f0.w};

        int dadj = dstp[e] - mn;
        if (dadj < 0) dadj += N_;   // NumPy negative-index wrap

        #pragma unroll
        for (int d = 0; d < D_; d++) {
            float m = 0.0f;
            #pragma unroll
            for (int k = 0; k < FE_; k++) m += a[k] * sWe[k * D_ + d];
            #pragma unroll
            for (int k = 0; k < FF_; k++) m += fv[k] * sWf[k * D_ + d];
            atomicAdd(&aggw[d * N_ + dadj], fmaxf(m, 0.0f));
        }
    }
    __syncthreads();

    // ---- phase 2: node update + seq write + u/v precompute ----
    const float* xg = x + (size_t)g * N_ * FX_;
    bf16_t* seqrow = seq + (size_t)g * SEQ_;
    for (int n = lane; n < N_; n += 64) {
        const float4* xp = (const float4*)(xg + (size_t)n * FX_);
        float4 x0 = xp[0], x1 = xp[1];
        float xi[FX_] = {x0.x, x0.y, x0.z, x0.w, x1.x, x1.y, x1.z, x1.w};

        float xo[D_];
        bf16x8 pk;
        #pragma unroll
        for (int d = 0; d < D_; d++) {
            float v = aggw[d * N_ + n];
            #pragma unroll
            for (int k = 0; k < FX_; k++) v += xi[k] * sWx[k * D_ + d];
            xo[d] = xi[d] + fmaxf(v, 0.0f);
            pk[d] = (bf16_t)xo[d];
        }
        *(bf16x8*)(seqrow + (size_t)n * D_) = pk;

        #pragma unroll
        for (int d = 0; d < D_; d++) {
            float uu = 0.0f, vv = 0.0f;
            #pragma unroll
            for (int k = 0; k < D_; k++) {
                uu += xo[k] * sWedge[k * D_ + d];
                vv += xo[k] * sWedge[(D_ + k) * D_ + d];
            }
            uw[d * N_ + n] = uu;
            vw[d * N_ + n] = vv;
        }
    }
    __syncthreads();

    // ---- phase 3: edge update ----
    for (int e = lane; e < E_; e += 64) {
        const float4* ap = (const float4*)(eag + (size_t)e * FE_);
        float4 a0 = ap[0], a1 = ap[1];
        float a[FE_] = {a0.x, a0.y, a0.z, a0.w, a1.x, a1.y, a1.z, a1.w};

        int sadj = srcp[e] - mn;                    // src-min >= 0 always
        int dadj = dstp[e] - mn;
        if (dadj < 0) dadj += N_;

        bf16x8 pk;
        #pragma unroll
        for (int d = 0; d < D_; d++) {
            float t = uw[d * N_ + sadj] + vw[d * N_ + dadj];
            #pragma unroll
            for (int k = 0; k < FE_; k++) t += a[k] * sWedge[(2 * D_ + k) * D_ + d];
            pk[d] = (bf16_t)(a[d] + fmaxf(t, 0.0f));
        }
        *(bf16x8*)(seqrow + XD_ + (size_t)e * D_) = pk;
    }
}

// ---------------- big-GEMM: 256x128 tile, BK=64, counted-vmcnt pipeline ----
// C[M,Nn] = A[M,K]bf16 @ Bm[Nn,K]bf16^T + bias.  Requires M%256==0, K%64==0.
// 8 waves (4M x 2N), per-wave 64x64 out (4x4 frags of 16x16x32).
// LDS: 2 buffers x (A 256x64 + B 128x64) bf16 = 96 KB.
// Schedule per K-tile t (buf c=t&1):
//   ds_read 16 frags -> MFMA 32 (compiler lgkm waits retire all reads)
//   s_barrier (B1: buf c reads retired by ALL waves)
//   STAGE(t+2 -> buf c)  [6 global_load_lds issues]
//   s_waitcnt vmcnt(6)   [tile t+1's 6 issues landed; t+2's 6 in flight]
//   s_barrier (B2: tile t+1 visible)
// LDS bank-conflict-free by construction: granule slot = g ^ (row&7), applied
// to the per-lane GLOBAL source (dest stays linear, rule m104/m231) and to the
// ds_read address (same involution both sides).
__global__ __launch_bounds__(512, 2) void mfma_gemm_big(
    const bf16_t* __restrict__ A,
    const bf16_t* __restrict__ Bm,
    const float*  __restrict__ bias,
    float* __restrict__ C,
    int M, int Nn, int K)
{
    constexpr int TBM = 256, TBN = 128, TBK = 64;
    __shared__ bf16_t As[2][TBM * TBK];   // 2 x 32 KB
    __shared__ bf16_t Bs[2][TBN * TBK];   // 2 x 16 KB

    const int tid  = threadIdx.x;
    const int wave = tid >> 6;
    const int lane = tid & 63;

    // XCD-aware chunked swizzle (grid is 760 = 8*95, %8==0 -> bijective)
    const int nbx = gridDim.x;
    const int cpx = nbx >> 3;
    const int bid = blockIdx.x;
    const int swz = (bid & 7) * cpx + (bid >> 3);
    const int ntn = (Nn + TBN - 1) / TBN;
    const int m0 = (swz / ntn) * TBM;
    const int n0 = (swz % ntn) * TBN;

    const int wr = wave >> 1;          // 0..3 -> M offset wr*64
    const int wc = wave & 1;           // 0..1 -> N offset wc*64

    // staging thread map: row r_loc (0..63 per issue), granule slot 0..7
    const int r_loc  = tid >> 3;
    const int s_slot = tid & 7;

    // frag addressing
    const int fr = lane & 15;
    const int fq = lane >> 4;          // 0..3

    f32x4 acc[4][4] = {};

    const int nkt = K / TBK;

    auto STAGE = [&](int t, int buf) {
        const size_t k0 = (size_t)t * TBK;
        #pragma unroll
        for (int i = 0; i < 4; i++) {
            int row = i * 64 + r_loc;                     // A tile row 0..255
            int gsl = s_slot ^ (row & 7);                 // inverse swizzle src
            const bf16_t* gp = A + (size_t)(m0 + row) * K + k0 + gsl * 8;
            async16(gp, &As[buf][row * TBK + s_slot * 8]);
        }
        #pragma unroll
        for (int i = 0; i < 2; i++) {
            int row = i * 64 + r_loc;                     // B tile row 0..127
            int gsl = s_slot ^ (row & 7);
            int br = n0 + row; if (br > Nn - 1) br = Nn - 1;
            const bf16_t* gp = Bm + (size_t)br * K + k0 + gsl * 8;
            async16(gp, &Bs[buf][row * TBK + s_slot * 8]);
        }
    };

    // prologue: tiles 0,1 in flight; wait tile 0 (6 newest = tile 1 stay out)
    STAGE(0, 0);
    STAGE(nkt > 1 ? 1 : 0, 1);
    asm volatile("s_waitcnt vmcnt(6)" ::: "memory");
    __builtin_amdgcn_sched_barrier(0);
    __builtin_amdgcn_s_barrier();

    for (int t = 0; t < nkt; ++t) {
        const int c = t & 1;
        const bf16_t* Ab = As[c];
        const bf16_t* Bb = Bs[c];

        bf16x8 af[2][4], bfr[2][4];
        #pragma unroll
        for (int kk = 0; kk < 2; kk++) {
            #pragma unroll
            for (int m = 0; m < 4; m++) {
                int r = wr * 64 + m * 16 + fr;
                int g = (kk * 4 + fq) ^ (r & 7);
                af[kk][m] = *(const bf16x8*)&Ab[r * TBK + g * 8];
            }
            #pragma unroll
            for (int n = 0; n < 4; n++) {
                int cc = wc * 64 + n * 16 + fr;
                int g = (kk * 4 + fq) ^ (cc & 7);
                bfr[kk][n] = *(const bf16x8*)&Bb[cc * TBK + g * 8];
            }
        }

        __builtin_amdgcn_s_setprio(1);
        #pragma unroll
        for (int kk = 0; kk < 2; kk++)
            #pragma unroll
            for (int m = 0; m < 4; m++)
                #pragma unroll
                for (int n = 0; n < 4; n++)
                    acc[m][n] = __builtin_amdgcn_mfma_f32_16x16x32_bf16(
                        af[kk][m], bfr[kk][n], acc[m][n], 0, 0, 0);
        __builtin_amdgcn_s_setprio(0);

        __builtin_amdgcn_sched_barrier(0);
        __builtin_amdgcn_s_barrier();     // B1: all reads of buf c retired

        int tn = t + 2; if (tn > nkt - 1) tn = nkt - 1;
        STAGE(tn, c);
        asm volatile("s_waitcnt vmcnt(6)" ::: "memory");
        __builtin_amdgcn_sched_barrier(0);
        __builtin_amdgcn_s_barrier();     // B2: tile t+1 visible
    }

    // C/D layout: col = lane&15, row = (lane>>4)*4 + reg  [m89/m91]
    const int crow = fq * 4;
    #pragma unroll
    for (int m = 0; m < 4; m++) {
        #pragma unroll
        for (int n = 0; n < 4; n++) {
            int row = m0 + wr * 64 + m * 16 + crow;
            int col = n0 + wc * 64 + n * 16 + fr;
            if (col < Nn) {
                float bv = bias[col];
                #pragma unroll
                for (int r = 0; r < 4; r++)
                    C[(size_t)(row + r) * Nn + col] = acc[m][n][r] + bv;
            }
        }
    }
}

// ---------------- bf16 MFMA GEMM (m97 structure) ----------------
// C[M,Nn] = A[M,K]_bf16 @ Bm[Nn,K]_bf16^T + bias[Nn]
// Tile 128x128, BK=32, 4 waves (2x2 of 64x64), 16x16x32 MFMA.
// Requires: M % 128 == 0, K % 32 == 0. Nn handled by clamp+mask.
template <typename OutT>
__global__ __launch_bounds__(256) void mfma_gemm_bt(
    const bf16_t* __restrict__ A,
    const bf16_t* __restrict__ Bm,
    const float*  __restrict__ bias,
    OutT* __restrict__ C,
    int M, int Nn, int K)
{
    __shared__ bf16_t As[128 * 32];
    __shared__ bf16_t Bs[128 * 32];

    const int tid  = threadIdx.x;
    const int wave = tid >> 6;
    const int lane = tid & 63;
    const int m0 = blockIdx.y * 128;
    const int n0 = blockIdx.x * 128;
    const int wm = (wave & 1) * 64;
    const int wn = (wave >> 1) * 64;

    // staging: each thread moves 16B; one issue = 64 rows x 32 k
    const int srow  = tid >> 2;        // 0..63
    const int skoff = (tid & 3) * 8;   // 0,8,16,24

    // fragment addressing (16x16x32): elem [fm][fk + j]
    const int fm = lane & 15;
    const int fk = (lane >> 4) * 8;

    f32x4 acc[4][4] = {};

    const bf16_t* a_ptr0 = A + (size_t)(m0 + srow) * K + skoff;
    const bf16_t* a_ptr1 = a_ptr0 + (size_t)64 * K;
    int brow0 = n0 + srow;      if (brow0 > Nn - 1) brow0 = Nn - 1;
    int brow1 = n0 + 64 + srow; if (brow1 > Nn - 1) brow1 = Nn - 1;
    const bf16_t* b_ptr0 = Bm + (size_t)brow0 * K + skoff;
    const bf16_t* b_ptr1 = Bm + (size_t)brow1 * K + skoff;

    bf16_t* lA0 = &As[srow * 32 + skoff];
    bf16_t* lA1 = &As[(64 + srow) * 32 + skoff];
    bf16_t* lB0 = &Bs[srow * 32 + skoff];
    bf16_t* lB1 = &Bs[(64 + srow) * 32 + skoff];

    for (int k0 = 0; k0 < K; k0 += 32) {
        async16(a_ptr0 + k0, lA0);
        async16(a_ptr1 + k0, lA1);
        async16(b_ptr0 + k0, lB0);
        async16(b_ptr1 + k0, lB1);
        __syncthreads();   // drains vmcnt: tiles staged

        bf16x8 af[4], bfm[4];
        #pragma unroll
        for (int i = 0; i < 4; i++)
            af[i] = *(const bf16x8*)&As[(wm + i * 16 + fm) * 32 + fk];
        #pragma unroll
        for (int j = 0; j < 4; j++)
            bfm[j] = *(const bf16x8*)&Bs[(wn + j * 16 + fm) * 32 + fk];

        #pragma unroll
        for (int i = 0; i < 4; i++)
            #pragma unroll
            for (int j = 0; j < 4; j++)
                acc[i][j] = __builtin_amdgcn_mfma_f32_16x16x32_bf16(
                    af[i], bfm[j], acc[i][j], 0, 0, 0);

        __syncthreads();   // all reads done before next overwrite
    }

    // C/D layout: col = lane&15, row = (lane>>4)*4 + reg  [m89/m91]
    const int crow = (lane >> 4) * 4;
    const int ccol = lane & 15;
    #pragma unroll
    for (int i = 0; i < 4; i++) {
        #pragma unroll
        for (int j = 0; j < 4; j++) {
            int row = m0 + wm + i * 16 + crow;
            int col = n0 + wn + j * 16 + ccol;
            if (col < Nn) {
                float bv = bias[col];
                #pragma unroll
                for (int r = 0; r < 4; r++) {
                    float v = acc[i][j][r] + bv;
                    C[(size_t)(row + r) * Nn + col] = (OutT)v;
                }
            }
        }
    }
}

// ---------------- fp32 -> bf16 flat convert ----------------
__global__ __launch_bounds__(256) void f2bf_kernel(
    const float* __restrict__ in, bf16_t* __restrict__ out, int n)
{
    int i = (blockIdx.x * 256 + threadIdx.x) * 4;
    if (i + 3 < n) {
        float4 v = *(const float4*)&in[i];
        out[i + 0] = (bf16_t)v.x;
        out[i + 1] = (bf16_t)v.y;
        out[i + 2] = (bf16_t)v.z;
        out[i + 3] = (bf16_t)v.w;
    } else {
        for (; i < n; i++) out[i] = (bf16_t)in[i];
    }
}

// ---------------- fp32 [K,N] -> bf16 [N,K] transpose-convert ----------------
__global__ __launch_bounds__(256) void tconv_kernel(
    const float* __restrict__ in, bf16_t* __restrict__ out, int K, int N)
{
    __shared__ float tile[32][33];
    int k0 = blockIdx.y * 32, n0 = blockIdx.x * 32;
    int tx = threadIdx.x & 31, ty = threadIdx.x >> 5;  // 32x8
    #pragma unroll
    for (int r = 0; r < 32; r += 8) {
        int k = k0 + ty + r, n = n0 + tx;
        tile[ty + r][tx] = (k < K && n < N) ? in[(size_t)k * N + n] : 0.0f;
    }
    __syncthreads();
    #pragma unroll
    for (int r = 0; r < 32; r += 8) {
        int n = n0 + ty + r, k = k0 + tx;
        if (n < N && k < K) out[(size_t)n * K + k] = (bf16_t)tile[tx][ty + r];
    }
}

// ---------------- GRU gate elementwise ----------------
__global__ __launch_bounds__(256) void gru_gates_kernel(
    const float* __restrict__ gi,   // [BS, 3H], row (b*S + t)
    const float* __restrict__ gh,   // [B, 3H]
    float*  __restrict__ h,         // [B, H] fp32 recurrence state
    bf16_t* __restrict__ hb,        // [B, H] bf16 copy (next-step GEMM A)
    bf16_t* __restrict__ yb,        // [B, S*H] bf16 (MLP GEMM A)
    int t)
{
    int i = blockIdx.x * blockDim.x + threadIdx.x;
    if (i >= B_ * H_) return;
    int b = i / H_;
    int j = i - b * H_;
    const float* girow = gi + ((size_t)b * S_ + t) * G3_;
    const float* ghrow = gh + (size_t)b * G3_;
    float r = sigmoidf_(girow[j] + ghrow[j]);
    float z = sigmoidf_(girow[H_ + j] + ghrow[H_ + j]);
    float n = tanhf(girow[2 * H_ + j] + r * ghrow[2 * H_ + j]);
    float hp = h[i];
    float hn = (1.0f - z) * n + z * hp;
    h[i] = hn;
    hb[i] = (bf16_t)hn;
    yb[(size_t)b * MIN_ + t * H_ + j] = (bf16_t)hn;
}

// ---------------- launch ----------------
extern "C" void kernel_launch(void* const* d_in, const int* in_sizes, int n_in,
                              void* d_out, int out_size, void* d_ws, size_t ws_size,
                              hipStream_t stream) {
    const float* x     = (const float*)d_in[0];
    const int*   ei    = (const int*)  d_in[1];
    const float* ef    = (const float*)d_in[2];
    const float* ea    = (const float*)d_in[3];
    const float* Wx    = (const float*)d_in[4];
    const float* We    = (const float*)d_in[5];
    const float* Wf    = (const float*)d_in[6];
    const float* Wedge = (const float*)d_in[7];
    const float* w_ih  = (const float*)d_in[8];
    const float* w_hh  = (const float*)d_in[9];
    const float* b_ih  = (const float*)d_in[10];
    const float* b_hh  = (const float*)d_in[11];
    const float* w1    = (const float*)d_in[12];
    const float* b1    = (const float*)d_in[13];
    const float* w2    = (const float*)d_in[14];
    const float* b2    = (const float*)d_in[15];
    float* out = (float*)d_out;

    // ---- workspace carve-up (bytes, 256-aligned) ----
    char* p = (char*)d_ws;
    auto alloc = [&](size_t bytes) {
        void* r = (void*)p;
        p += (bytes + 255) & ~(size_t)255;
        return r;
    };
    bf16_t* seq   = (bf16_t*)alloc((size_t)BS_ * SEQ_ * 2);   // 110.1 MB
    bf16_t* wihb  = (bf16_t*)alloc((size_t)G3_ * SEQ_ * 2);   //  25.8 MB
    bf16_t* whhb  = (bf16_t*)alloc((size_t)G3_ * H_ * 2);     //   3.8 MB
    bf16_t* w1t   = (bf16_t*)alloc((size_t)MH_ * MIN_ * 2);   //  10.2 MB
    bf16_t* w2t   = (bf16_t*)alloc((size_t)MO_ * MH_ * 2);    //   1.0 MB
    float*  gi    = (float*) alloc((size_t)BS_ * G3_ * 4);    //  98.3 MB
    float*  gh    = (float*) alloc((size_t)B_ * G3_ * 4);     //  19.7 MB
    float*  h     = (float*) alloc((size_t)B_ * H_ * 4);      //   6.6 MB
    bf16_t* hb    = (bf16_t*)alloc((size_t)B_ * H_ * 2);      //   3.3 MB
    bf16_t* yb    = (bf16_t*)alloc((size_t)B_ * MIN_ * 2);    //  16.4 MB
    bf16_t* t1b   = (bf16_t*)alloc((size_t)B_ * MH_ * 2);     //   5.2 MB

    // h0 = 0 (fp32 and bf16 views)
    hipMemsetAsync(h,  0, (size_t)B_ * H_ * sizeof(float), stream);
    hipMemsetAsync(hb, 0, (size_t)B_ * H_ * sizeof(bf16_t), stream);

    // weight converts
    {
        int n = G3_ * SEQ_;
        f2bf_kernel<<<(n / 4 + 255) / 256, 256, 0, stream>>>(w_ih, wihb, n);
    }
    {
        int n = G3_ * H_;
        f2bf_kernel<<<(n / 4 + 255) / 256, 256, 0, stream>>>(w_hh, whhb, n);
    }
    {   // w1 [MIN, MH] -> w1t [MH, MIN]
        dim3 grid((MH_ + 31) / 32, (MIN_ + 31) / 32);
        tconv_kernel<<<grid, 256, 0, stream>>>(w1, w1t, MIN_, MH_);
    }
    {   // w2 [MH, MO] -> w2t [MO, MH]
        dim3 grid((MO_ + 31) / 32, (MH_ + 31) / 32);
        tconv_kernel<<<grid, 256, 0, stream>>>(w2, w2t, MH_, MO_);
    }

    // GNN over all graphs -> seq (bf16); one wave per graph, 4 graphs/block
    gnn_kernel<<<BS_ / 4, 256, 0, stream>>>(x, ei, ef, ea, Wx, We, Wf, Wedge, seq);

    // gi = seq @ w_ih^T + b_ih  (all timesteps at once)
    // M=10240 (40 tiles), N=2400 (19 tiles of 128), K=5376 (84 K-tiles of 64)
    {
        int nblocks = (BS_ / 256) * ((G3_ + 127) / 128);   // 40*19 = 760
        mfma_gemm_big<<<nblocks, 512, 0, stream>>>(seq, wihb, b_ih, gi, BS_, G3_, SEQ_);
    }

    // GRU steps: gh = h @ w_hh^T + b_hh, then fused gates
    for (int t = 0; t < S_; t++) {
        dim3 grid((G3_ + 127) / 128, B_ / 128);    // 19 x 16
        mfma_gemm_bt<float><<<grid, 256, 0, stream>>>(hb, whhb, b_hh, gh, B_, G3_, H_);
        gru_gates_kernel<<<(B_ * H_ + 255) / 256, 256, 0, stream>>>(gi, gh, h, hb, yb, t);
    }

    // MLP: t1 = y @ w1 + b1 (bf16 out) ; out = t1 @ w2 + b2 (fp32 out)
    {
        dim3 grid((MH_ + 127) / 128, B_ / 128);    // 10 x 16
        mfma_gemm_bt<bf16_t><<<grid, 256, 0, stream>>>(yb, w1t, b1, t1b, B_, MH_, MIN_);
    }
    {
        dim3 grid((MO_ + 127) / 128, B_ / 128);    // 4 x 16
        mfma_gemm_bt<float><<<grid, 256, 0, stream>>>(t1b, w2t, b2, out, B_, MO_, MH_);
    }
}

// Round 3
// 1412.647 us; speedup vs baseline: 1.0668x; 1.0668x over previous
//
#include <hip/hip_runtime.h>
#include <math.h>

// ---------------- problem constants ----------------
constexpr int B_  = 2048;
constexpr int S_  = 5;
constexpr int N_  = 80;
constexpr int E_  = 592;
constexpr int FX_ = 8;
constexpr int FF_ = 4;
constexpr int FE_ = 8;
constexpr int D_  = 8;
constexpr int H_  = 800;

constexpr int BS_  = B_ * S_;         // 10240 graphs
constexpr int XD_  = N_ * D_;         // 640
constexpr int ED_  = E_ * D_;         // 4736
constexpr int SEQ_ = XD_ + ED_;       // 5376 (GRU input width)
constexpr int G3_  = 3 * H_;          // 2400
constexpr int MIN_ = S_ * H_;         // 4000 (mlp input width)
constexpr int MH_  = 1280;            // mlp hidden
constexpr int MO_  = S_ * 80;         // 400 (mlp output width)

typedef __bf16 bf16_t;
typedef __bf16 bf16x8 __attribute__((ext_vector_type(8)));
typedef float  f32x4  __attribute__((ext_vector_type(4)));

__device__ __forceinline__ float sigmoidf_(float x) {
    return 1.0f / (1.0f + expf(-x));
}

// async global->LDS, 16 bytes per lane (global_load_lds_dwordx4)
__device__ __forceinline__ void async16(const void* g, void* l) {
    __builtin_amdgcn_global_load_lds(
        (const __attribute__((address_space(1))) unsigned int*)g,
        (__attribute__((address_space(3))) unsigned int*)l,
        16, 0, 0);
}

// ---------------- GNN: one WAVE per (b,s) graph, 4 graphs per block ----------
__global__ __launch_bounds__(256, 4) void gnn_kernel(
    const float* __restrict__ x,      // [BS, N, FX]
    const int*   __restrict__ ei,     // [BS, 2, E]
    const float* __restrict__ ef,     // [BS, E, FF]
    const float* __restrict__ ea,     // [BS, E, FE]
    const float* __restrict__ Wx,     // [FX, D]
    const float* __restrict__ We,     // [FE, D]
    const float* __restrict__ Wf,     // [FF, D]
    const float* __restrict__ Wedge,  // [2D+FE=24, D]
    bf16_t* __restrict__ seq)         // [BS, SEQ] bf16
{
    const int tid  = threadIdx.x;
    const int w    = tid >> 6;
    const int lane = tid & 63;
    const int g    = blockIdx.x * 4 + w;

    __shared__ float sWx[FX_ * D_];      // 64
    __shared__ float sWe[FE_ * D_];      // 64
    __shared__ float sWf[FF_ * D_];      // 32
    __shared__ float sWedge[24 * D_];    // 192
    __shared__ float agg[4][D_ * N_];    // [wave][d*80+n]  2.5KB/wave
    __shared__ float su [4][D_ * N_];    // u = xout @ Wedge[0:8]
    __shared__ float sv [4][D_ * N_];    // v = xout @ Wedge[8:16]

    if (tid < 64) { sWx[tid] = Wx[tid]; sWe[tid] = We[tid]; }
    if (tid < 32) sWf[tid] = Wf[tid];
    if (tid < 192) sWedge[tid] = Wedge[tid];

    float* aggw = agg[w];
    float* uw   = su[w];
    float* vw   = sv[w];
    for (int i = lane; i < D_ * N_; i += 64) aggw[i] = 0.0f;

    const int* srcp = ei + (size_t)g * 2 * E_;
    const int* dstp = srcp + E_;

    // wave-local min of src (reference: min over edge_index[...,0,:])
    int lmin = 0x7fffffff;
    for (int e = lane; e < E_; e += 64) lmin = min(lmin, srcp[e]);
    #pragma unroll
    for (int off = 32; off; off >>= 1)
        lmin = min(lmin, __shfl_xor(lmin, off, 64));
    const int mn = lmin;

    __syncthreads();   // weights + agg-zero visible

    // ---- phase 1: edge messages, scatter-add into agg[d][n] ----
    const float* eag = ea + (size_t)g * E_ * FE_;
    const float* efg = ef + (size_t)g * E_ * FF_;
    for (int e = lane; e < E_; e += 64) {
        const float4* ap = (const float4*)(eag + (size_t)e * FE_);
        float4 a0 = ap[0], a1 = ap[1];
        float4 f0 = *(const float4*)(efg + (size_t)e * FF_);
        float a[FE_] = {a0.x, a0.y, a0.z, a0.w, a1.x, a1.y, a1.z, a1.w};
        float fv[FF_] = {f0.x, f0.y, f0.z, f0.w};

        int dadj = dstp[e] - mn;
        if (dadj < 0) dadj += N_;   // NumPy negative-index wrap

        #pragma unroll
        for (int d = 0; d < D_; d++) {
            float m = 0.0f;
            #pragma unroll
            for (int k = 0; k < FE_; k++) m += a[k] * sWe[k * D_ + d];
            #pragma unroll
            for (int k = 0; k < FF_; k++) m += fv[k] * sWf[k * D_ + d];
            atomicAdd(&aggw[d * N_ + dadj], fmaxf(m, 0.0f));
        }
    }
    __syncthreads();

    // ---- phase 2: node update + seq write + u/v precompute ----
    const float* xg = x + (size_t)g * N_ * FX_;
    bf16_t* seqrow = seq + (size_t)g * SEQ_;
    for (int n = lane; n < N_; n += 64) {
        const float4* xp = (const float4*)(xg + (size_t)n * FX_);
        float4 x0 = xp[0], x1 = xp[1];
        float xi[FX_] = {x0.x, x0.y, x0.z, x0.w, x1.x, x1.y, x1.z, x1.w};

        float xo[D_];
        bf16x8 pk;
        #pragma unroll
        for (int d = 0; d < D_; d++) {
            float v = aggw[d * N_ + n];
            #pragma unroll
            for (int k = 0; k < FX_; k++) v += xi[k] * sWx[k * D_ + d];
            xo[d] = xi[d] + fmaxf(v, 0.0f);
            pk[d] = (bf16_t)xo[d];
        }
        *(bf16x8*)(seqrow + (size_t)n * D_) = pk;

        #pragma unroll
        for (int d = 0; d < D_; d++) {
            float uu = 0.0f, vv = 0.0f;
            #pragma unroll
            for (int k = 0; k < D_; k++) {
                uu += xo[k] * sWedge[k * D_ + d];
                vv += xo[k] * sWedge[(D_ + k) * D_ + d];
            }
            uw[d * N_ + n] = uu;
            vw[d * N_ + n] = vv;
        }
    }
    __syncthreads();

    // ---- phase 3: edge update ----
    for (int e = lane; e < E_; e += 64) {
        const float4* ap = (const float4*)(eag + (size_t)e * FE_);
        float4 a0 = ap[0], a1 = ap[1];
        float a[FE_] = {a0.x, a0.y, a0.z, a0.w, a1.x, a1.y, a1.z, a1.w};

        int sadj = srcp[e] - mn;                    // src-min >= 0 always
        int dadj = dstp[e] - mn;
        if (dadj < 0) dadj += N_;

        bf16x8 pk;
        #pragma unroll
        for (int d = 0; d < D_; d++) {
            float t = uw[d * N_ + sadj] + vw[d * N_ + dadj];
            #pragma unroll
            for (int k = 0; k < FE_; k++) t += a[k] * sWedge[(2 * D_ + k) * D_ + d];
            pk[d] = (bf16_t)(a[d] + fmaxf(t, 0.0f));
        }
        *(bf16x8*)(seqrow + XD_ + (size_t)e * D_) = pk;
    }
}

// ---------------- 2-phase dbuf MFMA GEMM (T3 minimum-2-phase) ----------------
// C[M,Nn] = A[M,K]bf16 @ Bm[Nn,K]bf16^T + bias.  M%128==0, K%TBK==0.
// Tile 128x128, 4 waves (2x2 of 64x64), double-buffered LDS.
// Per K-tile: STAGE(t+1 -> other buf) FIRST, then ds_read+MFMA of tile t,
// then ONE vmcnt(0)+s_barrier. Prefetch latency hides under compute; with
// TBK=64 LDS=64KB -> 2 blocks/CU, TBK=32 LDS=32KB -> 5 blocks/CU, so
// independent blocks cover each other's barrier stalls.
// LDS conflict-free: granule slot = s ^ (row & GM) applied to per-lane GLOBAL
// source (dest linear, rule m104/m231) and to the ds_read address (same
// involution both sides). Proven 0 conflicts at TBK=64 (R1 counters).
template <int TBK, typename OutT>
__global__ __launch_bounds__(256) void gemm2ph(
    const bf16_t* __restrict__ A,
    const bf16_t* __restrict__ Bm,
    const float*  __restrict__ bias,
    OutT* __restrict__ C,
    int M, int Nn, int K)
{
    constexpr int GR  = TBK / 8;      // granules (16B slots) per row
    constexpr int GM  = GR - 1;       // granule xor mask
    constexpr int RPI = 256 / GR;     // rows per staging issue
    constexpr int NISS = 128 / RPI;   // issues per matrix per K-tile
    constexpr int KK  = TBK / 32;     // mfma k-steps per tile

    __shared__ bf16_t As[2][128 * TBK];
    __shared__ bf16_t Bs[2][128 * TBK];

    const int tid  = threadIdx.x;
    const int wave = tid >> 6;
    const int lane = tid & 63;

    // XCD-aware chunked swizzle (all grids used are % 8 == 0 -> bijective)
    const int nbx = gridDim.x;
    int swz = blockIdx.x;
    if ((nbx & 7) == 0) {
        int cpx = nbx >> 3;
        swz = (swz & 7) * cpx + (swz >> 3);
    }
    const int ntn = (Nn + 127) >> 7;
    const int m0 = (swz / ntn) * 128;
    const int n0 = (swz % ntn) * 128;

    const int wm = (wave & 1) * 64;
    const int wn = (wave >> 1) * 64;

    const int r_loc  = tid / GR;
    const int s_slot = tid % GR;

    const int fr = lane & 15;
    const int fq = lane >> 4;          // 0..3

    f32x4 acc[4][4] = {};
    const int nkt = K / TBK;

    auto STAGE = [&](int t, int buf) {
        const size_t k0 = (size_t)t * TBK;
        #pragma unroll
        for (int i = 0; i < NISS; i++) {
            int row = i * RPI + r_loc;
            int gsl = s_slot ^ (row & GM);            // inverse swizzle on src
            async16(A + (size_t)(m0 + row) * K + k0 + gsl * 8,
                    &As[buf][row * TBK + s_slot * 8]);
        }
        #pragma unroll
        for (int i = 0; i < NISS; i++) {
            int row = i * RPI + r_loc;
            int gsl = s_slot ^ (row & GM);
            int br = n0 + row; if (br > Nn - 1) br = Nn - 1;
            async16(Bm + (size_t)br * K + k0 + gsl * 8,
                    &Bs[buf][row * TBK + s_slot * 8]);
        }
    };

    // prologue: tile 0 staged and published
    STAGE(0, 0);
    asm volatile("s_waitcnt vmcnt(0)" ::: "memory");
    __builtin_amdgcn_sched_barrier(0);
    __builtin_amdgcn_s_barrier();

    for (int t = 0; t < nkt; ++t) {
        const int c = t & 1;
        int tn = t + 1; if (tn > nkt - 1) tn = nkt - 1;
        STAGE(tn, c ^ 1);              // issue next-tile loads FIRST

        const bf16_t* Ab = As[c];
        const bf16_t* Bb = Bs[c];
        bf16x8 af[KK][4], bfr[KK][4];
        #pragma unroll
        for (int kk = 0; kk < KK; kk++) {
            #pragma unroll
            for (int m = 0; m < 4; m++) {
                int r = wm + m * 16 + fr;
                int g = (kk * 4 + fq) ^ (r & GM);
                af[kk][m] = *(const bf16x8*)&Ab[r * TBK + g * 8];
            }
            #pragma unroll
            for (int n = 0; n < 4; n++) {
                int cc = wn + n * 16 + fr;
                int g = (kk * 4 + fq) ^ (cc & GM);
                bfr[kk][n] = *(const bf16x8*)&Bb[cc * TBK + g * 8];
            }
        }

        __builtin_amdgcn_s_setprio(1);
        #pragma unroll
        for (int kk = 0; kk < KK; kk++)
            #pragma unroll
            for (int m = 0; m < 4; m++)
                #pragma unroll
                for (int n = 0; n < 4; n++)
                    acc[m][n] = __builtin_amdgcn_mfma_f32_16x16x32_bf16(
                        af[kk][m], bfr[kk][n], acc[m][n], 0, 0, 0);
        __builtin_amdgcn_s_setprio(0);

        __builtin_amdgcn_sched_barrier(0);
        asm volatile("s_waitcnt vmcnt(0)" ::: "memory");  // tile t+1 landed
        __builtin_amdgcn_sched_barrier(0);
        __builtin_amdgcn_s_barrier();  // all reads of buf c retired, t+1 visible
    }

    // C/D layout: col = lane&15, row = (lane>>4)*4 + reg  [m89/m91]
    const int crow = fq * 4;
    #pragma unroll
    for (int m = 0; m < 4; m++) {
        #pragma unroll
        for (int n = 0; n < 4; n++) {
            int row = m0 + wm + m * 16 + crow;
            int col = n0 + wn + n * 16 + fr;
            if (col < Nn) {
                float bv = bias[col];
                #pragma unroll
                for (int r = 0; r < 4; r++) {
                    float v = acc[m][n][r] + bv;
                    C[(size_t)(row + r) * Nn + col] = (OutT)v;
                }
            }
        }
    }
}

// ---------------- fp32 -> bf16 flat convert ----------------
__global__ __launch_bounds__(256) void f2bf_kernel(
    const float* __restrict__ in, bf16_t* __restrict__ out, int n)
{
    int i = (blockIdx.x * 256 + threadIdx.x) * 4;
    if (i + 3 < n) {
        float4 v = *(const float4*)&in[i];
        out[i + 0] = (bf16_t)v.x;
        out[i + 1] = (bf16_t)v.y;
        out[i + 2] = (bf16_t)v.z;
        out[i + 3] = (bf16_t)v.w;
    } else {
        for (; i < n; i++) out[i] = (bf16_t)in[i];
    }
}

// ---------------- fp32 [K,N] -> bf16 [N,K] transpose-convert ----------------
__global__ __launch_bounds__(256) void tconv_kernel(
    const float* __restrict__ in, bf16_t* __restrict__ out, int K, int N)
{
    __shared__ float tile[32][33];
    int k0 = blockIdx.y * 32, n0 = blockIdx.x * 32;
    int tx = threadIdx.x & 31, ty = threadIdx.x >> 5;  // 32x8
    #pragma unroll
    for (int r = 0; r < 32; r += 8) {
        int k = k0 + ty + r, n = n0 + tx;
        tile[ty + r][tx] = (k < K && n < N) ? in[(size_t)k * N + n] : 0.0f;
    }
    __syncthreads();
    #pragma unroll
    for (int r = 0; r < 32; r += 8) {
        int n = n0 + ty + r, k = k0 + tx;
        if (n < N && k < K) out[(size_t)n * K + k] = (bf16_t)tile[tx][ty + r];
    }
}

// ---------------- GRU gate elementwise ----------------
__global__ __launch_bounds__(256) void gru_gates_kernel(
    const float* __restrict__ gi,   // [BS, 3H], row (b*S + t)
    const float* __restrict__ gh,   // [B, 3H]
    float*  __restrict__ h,         // [B, H] fp32 recurrence state
    bf16_t* __restrict__ hb,        // [B, H] bf16 copy (next-step GEMM A)
    bf16_t* __restrict__ yb,        // [B, S*H] bf16 (MLP GEMM A)
    int t)
{
    int i = blockIdx.x * blockDim.x + threadIdx.x;
    if (i >= B_ * H_) return;
    int b = i / H_;
    int j = i - b * H_;
    const float* girow = gi + ((size_t)b * S_ + t) * G3_;
    const float* ghrow = gh + (size_t)b * G3_;
    float r = sigmoidf_(girow[j] + ghrow[j]);
    float z = sigmoidf_(girow[H_ + j] + ghrow[H_ + j]);
    float n = tanhf(girow[2 * H_ + j] + r * ghrow[2 * H_ + j]);
    float hp = h[i];
    float hn = (1.0f - z) * n + z * hp;
    h[i] = hn;
    hb[i] = (bf16_t)hn;
    yb[(size_t)b * MIN_ + t * H_ + j] = (bf16_t)hn;
}

// ---------------- launch ----------------
extern "C" void kernel_launch(void* const* d_in, const int* in_sizes, int n_in,
                              void* d_out, int out_size, void* d_ws, size_t ws_size,
                              hipStream_t stream) {
    const float* x     = (const float*)d_in[0];
    const int*   ei    = (const int*)  d_in[1];
    const float* ef    = (const float*)d_in[2];
    const float* ea    = (const float*)d_in[3];
    const float* Wx    = (const float*)d_in[4];
    const float* We    = (const float*)d_in[5];
    const float* Wf    = (const float*)d_in[6];
    const float* Wedge = (const float*)d_in[7];
    const float* w_ih  = (const float*)d_in[8];
    const float* w_hh  = (const float*)d_in[9];
    const float* b_ih  = (const float*)d_in[10];
    const float* b_hh  = (const float*)d_in[11];
    const float* w1    = (const float*)d_in[12];
    const float* b1    = (const float*)d_in[13];
    const float* w2    = (const float*)d_in[14];
    const float* b2    = (const float*)d_in[15];
    float* out = (float*)d_out;

    // ---- workspace carve-up (bytes, 256-aligned) ----
    char* p = (char*)d_ws;
    auto alloc = [&](size_t bytes) {
        void* r = (void*)p;
        p += (bytes + 255) & ~(size_t)255;
        return r;
    };
    bf16_t* seq   = (bf16_t*)alloc((size_t)BS_ * SEQ_ * 2);   // 110.1 MB
    bf16_t* wihb  = (bf16_t*)alloc((size_t)G3_ * SEQ_ * 2);   //  25.8 MB
    bf16_t* whhb  = (bf16_t*)alloc((size_t)G3_ * H_ * 2);     //   3.8 MB
    bf16_t* w1t   = (bf16_t*)alloc((size_t)MH_ * MIN_ * 2);   //  10.2 MB
    bf16_t* w2t   = (bf16_t*)alloc((size_t)MO_ * MH_ * 2);    //   1.0 MB
    float*  gi    = (float*) alloc((size_t)BS_ * G3_ * 4);    //  98.3 MB
    float*  gh    = (float*) alloc((size_t)B_ * G3_ * 4);     //  19.7 MB
    float*  h     = (float*) alloc((size_t)B_ * H_ * 4);      //   6.6 MB
    bf16_t* hb    = (bf16_t*)alloc((size_t)B_ * H_ * 2);      //   3.3 MB
    bf16_t* yb    = (bf16_t*)alloc((size_t)B_ * MIN_ * 2);    //  16.4 MB
    bf16_t* t1b   = (bf16_t*)alloc((size_t)B_ * MH_ * 2);     //   5.2 MB

    // h0 = 0 (fp32 and bf16 views)
    hipMemsetAsync(h,  0, (size_t)B_ * H_ * sizeof(float), stream);
    hipMemsetAsync(hb, 0, (size_t)B_ * H_ * sizeof(bf16_t), stream);

    // weight converts
    {
        int n = G3_ * SEQ_;
        f2bf_kernel<<<(n / 4 + 255) / 256, 256, 0, stream>>>(w_ih, wihb, n);
    }
    {
        int n = G3_ * H_;
        f2bf_kernel<<<(n / 4 + 255) / 256, 256, 0, stream>>>(w_hh, whhb, n);
    }
    {   // w1 [MIN, MH] -> w1t [MH, MIN]
        dim3 grid((MH_ + 31) / 32, (MIN_ + 31) / 32);
        tconv_kernel<<<grid, 256, 0, stream>>>(w1, w1t, MIN_, MH_);
    }
    {   // w2 [MH, MO] -> w2t [MO, MH]
        dim3 grid((MO_ + 31) / 32, (MH_ + 31) / 32);
        tconv_kernel<<<grid, 256, 0, stream>>>(w2, w2t, MH_, MO_);
    }

    // GNN over all graphs -> seq (bf16); one wave per graph, 4 graphs/block
    gnn_kernel<<<BS_ / 4, 256, 0, stream>>>(x, ei, ef, ea, Wx, We, Wf, Wedge, seq);

    // gi = seq @ w_ih^T + b_ih  (all timesteps at once)
    // M=10240 (80 tiles of 128), N=2400 (19 tiles), K=5376 (84 K-tiles of 64)
    {
        int nblocks = (BS_ / 128) * ((G3_ + 127) / 128);   // 80*19 = 1520
        gemm2ph<64, float><<<nblocks, 256, 0, stream>>>(seq, wihb, b_ih, gi, BS_, G3_, SEQ_);
    }

    // GRU steps: gh = h @ w_hh^T + b_hh, then fused gates
    for (int t = 0; t < S_; t++) {
        int nblocks = (B_ / 128) * ((G3_ + 127) / 128);    // 16*19 = 304
        gemm2ph<32, float><<<nblocks, 256, 0, stream>>>(hb, whhb, b_hh, gh, B_, G3_, H_);
        gru_gates_kernel<<<(B_ * H_ + 255) / 256, 256, 0, stream>>>(gi, gh, h, hb, yb, t);
    }

    // MLP: t1 = y @ w1 + b1 (bf16 out) ; out = t1 @ w2 + b2 (fp32 out)
    {
        int nblocks = (B_ / 128) * ((MH_ + 127) / 128);    // 16*10 = 160
        gemm2ph<32, bf16_t><<<nblocks, 256, 0, stream>>>(yb, w1t, b1, t1b, B_, MH_, MIN_);
    }
    {
        int nblocks = (B_ / 128) * ((MO_ + 127) / 128);    // 16*4 = 64
        gemm2ph<32, float><<<nblocks, 256, 0, stream>>>(t1b, w2t, b2, out, B_, MO_, MH_);
    }
}

// Round 4
// 1340.629 us; speedup vs baseline: 1.1241x; 1.0537x over previous
//
#include <hip/hip_runtime.h>
#include <math.h>

// ---------------- problem constants ----------------
constexpr int B_  = 2048;
constexpr int S_  = 5;
constexpr int N_  = 80;
constexpr int E_  = 592;
constexpr int FX_ = 8;
constexpr int FF_ = 4;
constexpr int FE_ = 8;
constexpr int D_  = 8;
constexpr int H_  = 800;

constexpr int BS_  = B_ * S_;         // 10240 graphs
constexpr int XD_  = N_ * D_;         // 640
constexpr int ED_  = E_ * D_;         // 4736
constexpr int SEQ_ = XD_ + ED_;       // 5376 (GRU input width)
constexpr int G3_  = 3 * H_;          // 2400
constexpr int MIN_ = S_ * H_;         // 4000 (mlp input width)
constexpr int MH_  = 1280;            // mlp hidden
constexpr int MO_  = S_ * 80;         // 400 (mlp output width)

typedef __bf16 bf16_t;
typedef __bf16 bf16x8 __attribute__((ext_vector_type(8)));
typedef float  f32x4  __attribute__((ext_vector_type(4)));

__device__ __forceinline__ float sigmoidf_(float x) {
    return 1.0f / (1.0f + expf(-x));
}

// async global->LDS, 16 bytes per lane (global_load_lds_dwordx4)
__device__ __forceinline__ void async16(const void* g, void* l) {
    __builtin_amdgcn_global_load_lds(
        (const __attribute__((address_space(1))) unsigned int*)g,
        (__attribute__((address_space(3))) unsigned int*)l,
        16, 0, 0);
}

// acc += s * (*w), componentwise; w in LDS -> ds_read_b128
__device__ __forceinline__ void fma4(float4& a, float s, const float* w) {
    float4 ww = *(const float4*)w;
    a.x += s * ww.x; a.y += s * ww.y; a.z += s * ww.z; a.w += s * ww.w;
}

// ---------------- GNN: one WAVE per (b,s) graph, 4 graphs per block ----------
// Barrier-free: each wave owns its agg/uv partition; the shared weight copy is
// written by EVERY wave with identical values (word-atomic benign race), so a
// wave only needs its own lgkmcnt(0) before reading. Weight FMAs consume LDS
// via ds_read_b128 quads (4 FMA per read). Edge loops use rotating prefetch.
__global__ __launch_bounds__(256) void gnn_kernel(
    const float* __restrict__ x,      // [BS, N, FX]
    const int*   __restrict__ ei,     // [BS, 2, E]
    const float* __restrict__ ef,     // [BS, E, FF]
    const float* __restrict__ ea,     // [BS, E, FE]
    const float* __restrict__ Wx,     // [FX, D]
    const float* __restrict__ We,     // [FE, D]
    const float* __restrict__ Wf,     // [FF, D]
    const float* __restrict__ Wedge,  // [2D+FE=24, D]
    bf16_t* __restrict__ seq)         // [BS, SEQ] bf16
{
    constexpr int UVP = 20;           // padded uv row stride (floats, 16B-aligned)
    const int tid  = threadIdx.x;
    const int w    = tid >> 6;
    const int lane = tid & 63;
    const int g    = blockIdx.x * 4 + w;

    // [0:64) Wx | [64:128) We | [128:160) Wf | [160:352) Wedge(24x8)
    __shared__ float sW[352];
    __shared__ float agg[4][D_ * N_];     // per wave, [d*80+n]
    __shared__ float uv [4][N_ * UVP];    // per wave, [n*20 + (0..7 u | 8..15 v)]

    // every wave writes the same values (benign identical-value race)
    sW[160 + lane]       = Wedge[lane];
    sW[160 + 64 + lane]  = Wedge[64 + lane];
    sW[160 + 128 + lane] = Wedge[128 + lane];
    sW[lane]      = Wx[lane];
    sW[64 + lane] = We[lane];
    if (lane < 32) sW[128 + lane] = Wf[lane];

    float* aggw = agg[w];
    float* uvw  = uv[w];
    #pragma unroll
    for (int i = 0; i < 10; i++) aggw[lane + i * 64] = 0.0f;  // 640 = 10*64

    const int* srcp = ei + (size_t)g * 2 * E_;
    const int* dstp = srcp + E_;

    // wave-local min of src (reference: min over edge_index[...,0,:])
    int lmin = 0x7fffffff;
    for (int e = lane; e < E_; e += 64) lmin = min(lmin, srcp[e]);
    #pragma unroll
    for (int off = 32; off; off >>= 1)
        lmin = min(lmin, __shfl_xor(lmin, off, 64));
    const int mn = lmin;

    asm volatile("s_waitcnt lgkmcnt(0)" ::: "memory");  // weights + zeros (this wave)

    const float* eag = ea + (size_t)g * E_ * FE_;
    const float* efg = ef + (size_t)g * E_ * FF_;
    const float* sWe_ = sW + 64;
    const float* sWf_ = sW + 128;

    // ---- phase 1: edge messages, scatter-add into agg[d][n] ----
    auto edge_msg = [&](float4 a0, float4 a1, float4 f, int dn) {
        float aa[8]  = {a0.x, a0.y, a0.z, a0.w, a1.x, a1.y, a1.z, a1.w};
        float ffv[4] = {f.x, f.y, f.z, f.w};
        float4 mlo = {0, 0, 0, 0}, mhi = {0, 0, 0, 0};
        #pragma unroll
        for (int k = 0; k < 8; k++) {
            fma4(mlo, aa[k], &sWe_[k * 8]);
            fma4(mhi, aa[k], &sWe_[k * 8 + 4]);
        }
        #pragma unroll
        for (int k = 0; k < 4; k++) {
            fma4(mlo, ffv[k], &sWf_[k * 8]);
            fma4(mhi, ffv[k], &sWf_[k * 8 + 4]);
        }
        atomicAdd(&aggw[0 * N_ + dn], fmaxf(mlo.x, 0.0f));
        atomicAdd(&aggw[1 * N_ + dn], fmaxf(mlo.y, 0.0f));
        atomicAdd(&aggw[2 * N_ + dn], fmaxf(mlo.z, 0.0f));
        atomicAdd(&aggw[3 * N_ + dn], fmaxf(mlo.w, 0.0f));
        atomicAdd(&aggw[4 * N_ + dn], fmaxf(mhi.x, 0.0f));
        atomicAdd(&aggw[5 * N_ + dn], fmaxf(mhi.y, 0.0f));
        atomicAdd(&aggw[6 * N_ + dn], fmaxf(mhi.z, 0.0f));
        atomicAdd(&aggw[7 * N_ + dn], fmaxf(mhi.w, 0.0f));
    };

    float4 ca0, ca1, cf; int cdn;
    {
        const float4* ap = (const float4*)(eag + (size_t)lane * FE_);
        ca0 = ap[0]; ca1 = ap[1];
        cf  = *(const float4*)(efg + (size_t)lane * FF_);
        int dd = dstp[lane] - mn; if (dd < 0) dd += N_;
        cdn = dd;
    }
    for (int i = 0; i < 9; i++) {          // compute e=lane+i*64, prefetch next
        int en = lane + (i + 1) * 64;
        int ec = (en < E_) ? en : 0;
        const float4* ap = (const float4*)(eag + (size_t)ec * FE_);
        float4 na0 = ap[0], na1 = ap[1];
        float4 nf  = *(const float4*)(efg + (size_t)ec * FF_);
        int dd = dstp[ec] - mn; if (dd < 0) dd += N_;

        edge_msg(ca0, ca1, cf, cdn);
        ca0 = na0; ca1 = na1; cf = nf; cdn = dd;
    }
    if (lane < 16) edge_msg(ca0, ca1, cf, cdn);   // tail e = 576+lane

    asm volatile("s_waitcnt lgkmcnt(0)" ::: "memory");  // atomics done (this wave)

    // ---- phase 2: node update + seq write + u/v precompute ----
    const float* xg = x + (size_t)g * N_ * FX_;
    bf16_t* seqrow = seq + (size_t)g * SEQ_;
    const float* sWx_  = sW;
    const float* sWu_  = sW + 160;        // Wedge rows 0..7
    const float* sWv_  = sW + 160 + 64;   // Wedge rows 8..15
    #pragma unroll
    for (int it = 0; it < 2; it++) {
        int n = lane + it * 64;
        if (n < N_) {
            const float4* xp = (const float4*)(xg + (size_t)n * FX_);
            float4 x0 = xp[0], x1 = xp[1];
            float xi[8] = {x0.x, x0.y, x0.z, x0.w, x1.x, x1.y, x1.z, x1.w};

            float4 vlo = {aggw[0 * N_ + n], aggw[1 * N_ + n],
                          aggw[2 * N_ + n], aggw[3 * N_ + n]};
            float4 vhi = {aggw[4 * N_ + n], aggw[5 * N_ + n],
                          aggw[6 * N_ + n], aggw[7 * N_ + n]};
            #pragma unroll
            for (int k = 0; k < 8; k++) {
                fma4(vlo, xi[k], &sWx_[k * 8]);
                fma4(vhi, xi[k], &sWx_[k * 8 + 4]);
            }
            float xo[8];
            xo[0] = xi[0] + fmaxf(vlo.x, 0.0f); xo[1] = xi[1] + fmaxf(vlo.y, 0.0f);
            xo[2] = xi[2] + fmaxf(vlo.z, 0.0f); xo[3] = xi[3] + fmaxf(vlo.w, 0.0f);
            xo[4] = xi[4] + fmaxf(vhi.x, 0.0f); xo[5] = xi[5] + fmaxf(vhi.y, 0.0f);
            xo[6] = xi[6] + fmaxf(vhi.z, 0.0f); xo[7] = xi[7] + fmaxf(vhi.w, 0.0f);

            bf16x8 pk;
            #pragma unroll
            for (int d = 0; d < 8; d++) pk[d] = (bf16_t)xo[d];
            *(bf16x8*)(seqrow + (size_t)n * D_) = pk;

            float4 ulo = {0,0,0,0}, uhi = {0,0,0,0};
            float4 wlo = {0,0,0,0}, whi = {0,0,0,0};
            #pragma unroll
            for (int k = 0; k < 8; k++) {
                fma4(ulo, xo[k], &sWu_[k * 8]);
                fma4(uhi, xo[k], &sWu_[k * 8 + 4]);
                fma4(wlo, xo[k], &sWv_[k * 8]);
                fma4(whi, xo[k], &sWv_[k * 8 + 4]);
            }
            *(float4*)&uvw[n * UVP + 0]  = ulo;
            *(float4*)&uvw[n * UVP + 4]  = uhi;
            *(float4*)&uvw[n * UVP + 8]  = wlo;
            *(float4*)&uvw[n * UVP + 12] = whi;
        }
    }
    asm volatile("s_waitcnt lgkmcnt(0)" ::: "memory");  // uv visible (this wave)

    // ---- phase 3: edge update ----
    const float* sW3 = sW + 160 + 128;    // Wedge rows 16..23
    auto edge_upd = [&](float4 a0, float4 a1, int sn, int dn, int e) {
        float aa[8] = {a0.x, a0.y, a0.z, a0.w, a1.x, a1.y, a1.z, a1.w};
        float4 tlo = *(const float4*)&uvw[sn * UVP];
        float4 thi = *(const float4*)&uvw[sn * UVP + 4];
        float4 qlo = *(const float4*)&uvw[dn * UVP + 8];
        float4 qhi = *(const float4*)&uvw[dn * UVP + 12];
        tlo.x += qlo.x; tlo.y += qlo.y; tlo.z += qlo.z; tlo.w += qlo.w;
        thi.x += qhi.x; thi.y += qhi.y; thi.z += qhi.z; thi.w += qhi.w;
        #pragma unroll
        for (int k = 0; k < 8; k++) {
            fma4(tlo, aa[k], &sW3[k * 8]);
            fma4(thi, aa[k], &sW3[k * 8 + 4]);
        }
        bf16x8 pk;
        pk[0] = (bf16_t)(aa[0] + fmaxf(tlo.x, 0.0f));
        pk[1] = (bf16_t)(aa[1] + fmaxf(tlo.y, 0.0f));
        pk[2] = (bf16_t)(aa[2] + fmaxf(tlo.z, 0.0f));
        pk[3] = (bf16_t)(aa[3] + fmaxf(tlo.w, 0.0f));
        pk[4] = (bf16_t)(aa[4] + fmaxf(thi.x, 0.0f));
        pk[5] = (bf16_t)(aa[5] + fmaxf(thi.y, 0.0f));
        pk[6] = (bf16_t)(aa[6] + fmaxf(thi.z, 0.0f));
        pk[7] = (bf16_t)(aa[7] + fmaxf(thi.w, 0.0f));
        *(bf16x8*)(seqrow + XD_ + (size_t)e * D_) = pk;
    };

    int csn, cdn2;
    {
        const float4* ap = (const float4*)(eag + (size_t)lane * FE_);
        ca0 = ap[0]; ca1 = ap[1];
        csn = srcp[lane] - mn;                       // src - min >= 0 always
        int dd = dstp[lane] - mn; if (dd < 0) dd += N_;
        cdn2 = dd;
    }
    for (int i = 0; i < 9; i++) {
        int en = lane + (i + 1) * 64;
        int ec = (en < E_) ? en : 0;
        const float4* ap = (const float4*)(eag + (size_t)ec * FE_);
        float4 na0 = ap[0], na1 = ap[1];
        int nsn = srcp[ec] - mn;
        int dd = dstp[ec] - mn; if (dd < 0) dd += N_;

        edge_upd(ca0, ca1, csn, cdn2, lane + i * 64);
        ca0 = na0; ca1 = na1; csn = nsn; cdn2 = dd;
    }
    if (lane < 16) edge_upd(ca0, ca1, csn, cdn2, 576 + lane);
}

// ---------------- 2-phase dbuf MFMA GEMM (T3 minimum-2-phase) ----------------
// C[M,Nn] = A[M,K]bf16 @ Bm[Nn,K]bf16^T + bias.  M%128==0, K%TBK==0.
// Tile 128x128, 4 waves (2x2 of 64x64), double-buffered LDS.
// Per K-tile: STAGE(t+1 -> other buf) FIRST, then ds_read+MFMA of tile t,
// then ONE vmcnt(0)+s_barrier.
template <int TBK, typename OutT>
__global__ __launch_bounds__(256) void gemm2ph(
    const bf16_t* __restrict__ A,
    const bf16_t* __restrict__ Bm,
    const float*  __restrict__ bias,
    OutT* __restrict__ C,
    int M, int Nn, int K)
{
    constexpr int GR  = TBK / 8;      // granules (16B slots) per row
    constexpr int GM  = GR - 1;       // granule xor mask
    constexpr int RPI = 256 / GR;     // rows per staging issue
    constexpr int NISS = 128 / RPI;   // issues per matrix per K-tile
    constexpr int KK  = TBK / 32;     // mfma k-steps per tile

    __shared__ bf16_t As[2][128 * TBK];
    __shared__ bf16_t Bs[2][128 * TBK];

    const int tid  = threadIdx.x;
    const int wave = tid >> 6;
    const int lane = tid & 63;

    // XCD-aware chunked swizzle (all grids used are % 8 == 0 -> bijective)
    const int nbx = gridDim.x;
    int swz = blockIdx.x;
    if ((nbx & 7) == 0) {
        int cpx = nbx >> 3;
        swz = (swz & 7) * cpx + (swz >> 3);
    }
    const int ntn = (Nn + 127) >> 7;
    const int m0 = (swz / ntn) * 128;
    const int n0 = (swz % ntn) * 128;

    const int wm = (wave & 1) * 64;
    const int wn = (wave >> 1) * 64;

    const int r_loc  = tid / GR;
    const int s_slot = tid % GR;

    const int fr = lane & 15;
    const int fq = lane >> 4;          // 0..3

    f32x4 acc[4][4] = {};
    const int nkt = K / TBK;

    auto STAGE = [&](int t, int buf) {
        const size_t k0 = (size_t)t * TBK;
        #pragma unroll
        for (int i = 0; i < NISS; i++) {
            int row = i * RPI + r_loc;
            int gsl = s_slot ^ (row & GM);            // inverse swizzle on src
            async16(A + (size_t)(m0 + row) * K + k0 + gsl * 8,
                    &As[buf][row * TBK + s_slot * 8]);
        }
        #pragma unroll
        for (int i = 0; i < NISS; i++) {
            int row = i * RPI + r_loc;
            int gsl = s_slot ^ (row & GM);
            int br = n0 + row; if (br > Nn - 1) br = Nn - 1;
            async16(Bm + (size_t)br * K + k0 + gsl * 8,
                    &Bs[buf][row * TBK + s_slot * 8]);
        }
    };

    // prologue: tile 0 staged and published
    STAGE(0, 0);
    asm volatile("s_waitcnt vmcnt(0)" ::: "memory");
    __builtin_amdgcn_sched_barrier(0);
    __builtin_amdgcn_s_barrier();

    for (int t = 0; t < nkt; ++t) {
        const int c = t & 1;
        int tn = t + 1; if (tn > nkt - 1) tn = nkt - 1;
        STAGE(tn, c ^ 1);              // issue next-tile loads FIRST

        const bf16_t* Ab = As[c];
        const bf16_t* Bb = Bs[c];
        bf16x8 af[KK][4], bfr[KK][4];
        #pragma unroll
        for (int kk = 0; kk < KK; kk++) {
            #pragma unroll
            for (int m = 0; m < 4; m++) {
                int r = wm + m * 16 + fr;
                int g = (kk * 4 + fq) ^ (r & GM);
                af[kk][m] = *(const bf16x8*)&Ab[r * TBK + g * 8];
            }
            #pragma unroll
            for (int n = 0; n < 4; n++) {
                int cc = wn + n * 16 + fr;
                int g = (kk * 4 + fq) ^ (cc & GM);
                bfr[kk][n] = *(const bf16x8*)&Bb[cc * TBK + g * 8];
            }
        }

        __builtin_amdgcn_s_setprio(1);
        #pragma unroll
        for (int kk = 0; kk < KK; kk++)
            #pragma unroll
            for (int m = 0; m < 4; m++)
                #pragma unroll
                for (int n = 0; n < 4; n++)
                    acc[m][n] = __builtin_amdgcn_mfma_f32_16x16x32_bf16(
                        af[kk][m], bfr[kk][n], acc[m][n], 0, 0, 0);
        __builtin_amdgcn_s_setprio(0);

        __builtin_amdgcn_sched_barrier(0);
        asm volatile("s_waitcnt vmcnt(0)" ::: "memory");  // tile t+1 landed
        __builtin_amdgcn_sched_barrier(0);
        __builtin_amdgcn_s_barrier();  // all reads of buf c retired, t+1 visible
    }

    // C/D layout: col = lane&15, row = (lane>>4)*4 + reg  [m89/m91]
    const int crow = fq * 4;
    #pragma unroll
    for (int m = 0; m < 4; m++) {
        #pragma unroll
        for (int n = 0; n < 4; n++) {
            int row = m0 + wm + m * 16 + crow;
            int col = n0 + wn + n * 16 + fr;
            if (col < Nn) {
                float bv = bias[col];
                #pragma unroll
                for (int r = 0; r < 4; r++) {
                    float v = acc[m][n][r] + bv;
                    C[(size_t)(row + r) * Nn + col] = (OutT)v;
                }
            }
        }
    }
}

// ---------------- fp32 -> bf16 flat convert ----------------
__global__ __launch_bounds__(256) void f2bf_kernel(
    const float* __restrict__ in, bf16_t* __restrict__ out, int n)
{
    int i = (blockIdx.x * 256 + threadIdx.x) * 4;
    if (i + 3 < n) {
        float4 v = *(const float4*)&in[i];
        out[i + 0] = (bf16_t)v.x;
        out[i + 1] = (bf16_t)v.y;
        out[i + 2] = (bf16_t)v.z;
        out[i + 3] = (bf16_t)v.w;
    } else {
        for (; i < n; i++) out[i] = (bf16_t)in[i];
    }
}

// ---------------- fp32 [K,N] -> bf16 [N,K] transpose-convert ----------------
__global__ __launch_bounds__(256) void tconv_kernel(
    const float* __restrict__ in, bf16_t* __restrict__ out, int K, int N)
{
    __shared__ float tile[32][33];
    int k0 = blockIdx.y * 32, n0 = blockIdx.x * 32;
    int tx = threadIdx.x & 31, ty = threadIdx.x >> 5;  // 32x8
    #pragma unroll
    for (int r = 0; r < 32; r += 8) {
        int k = k0 + ty + r, n = n0 + tx;
        tile[ty + r][tx] = (k < K && n < N) ? in[(size_t)k * N + n] : 0.0f;
    }
    __syncthreads();
    #pragma unroll
    for (int r = 0; r < 32; r += 8) {
        int n = n0 + ty + r, k = k0 + tx;
        if (n < N && k < K) out[(size_t)n * K + k] = (bf16_t)tile[tx][ty + r];
    }
}

// ---------------- GRU gate elementwise ----------------
__global__ __launch_bounds__(256) void gru_gates_kernel(
    const float* __restrict__ gi,   // [BS, 3H], row (b*S + t)
    const float* __restrict__ gh,   // [B, 3H]
    float*  __restrict__ h,         // [B, H] fp32 recurrence state
    bf16_t* __restrict__ hb,        // [B, H] bf16 copy (next-step GEMM A)
    bf16_t* __restrict__ yb,        // [B, S*H] bf16 (MLP GEMM A)
    int t)
{
    int i = blockIdx.x * blockDim.x + threadIdx.x;
    if (i >= B_ * H_) return;
    int b = i / H_;
    int j = i - b * H_;
    const float* girow = gi + ((size_t)b * S_ + t) * G3_;
    const float* ghrow = gh + (size_t)b * G3_;
    float r = sigmoidf_(girow[j] + ghrow[j]);
    float z = sigmoidf_(girow[H_ + j] + ghrow[H_ + j]);
    float n = tanhf(girow[2 * H_ + j] + r * ghrow[2 * H_ + j]);
    float hp = h[i];
    float hn = (1.0f - z) * n + z * hp;
    h[i] = hn;
    hb[i] = (bf16_t)hn;
    yb[(size_t)b * MIN_ + t * H_ + j] = (bf16_t)hn;
}

// ---------------- launch ----------------
extern "C" void kernel_launch(void* const* d_in, const int* in_sizes, int n_in,
                              void* d_out, int out_size, void* d_ws, size_t ws_size,
                              hipStream_t stream) {
    const float* x     = (const float*)d_in[0];
    const int*   ei    = (const int*)  d_in[1];
    const float* ef    = (const float*)d_in[2];
    const float* ea    = (const float*)d_in[3];
    const float* Wx    = (const float*)d_in[4];
    const float* We    = (const float*)d_in[5];
    const float* Wf    = (const float*)d_in[6];
    const float* Wedge = (const float*)d_in[7];
    const float* w_ih  = (const float*)d_in[8];
    const float* w_hh  = (const float*)d_in[9];
    const float* b_ih  = (const float*)d_in[10];
    const float* b_hh  = (const float*)d_in[11];
    const float* w1    = (const float*)d_in[12];
    const float* b1    = (const float*)d_in[13];
    const float* w2    = (const float*)d_in[14];
    const float* b2    = (const float*)d_in[15];
    float* out = (float*)d_out;

    // ---- workspace carve-up (bytes, 256-aligned) ----
    char* p = (char*)d_ws;
    auto alloc = [&](size_t bytes) {
        void* r = (void*)p;
        p += (bytes + 255) & ~(size_t)255;
        return r;
    };
    bf16_t* seq   = (bf16_t*)alloc((size_t)BS_ * SEQ_ * 2);   // 110.1 MB
    bf16_t* wihb  = (bf16_t*)alloc((size_t)G3_ * SEQ_ * 2);   //  25.8 MB
    bf16_t* whhb  = (bf16_t*)alloc((size_t)G3_ * H_ * 2);     //   3.8 MB
    bf16_t* w1t   = (bf16_t*)alloc((size_t)MH_ * MIN_ * 2);   //  10.2 MB
    bf16_t* w2t   = (bf16_t*)alloc((size_t)MO_ * MH_ * 2);    //   1.0 MB
    float*  gi    = (float*) alloc((size_t)BS_ * G3_ * 4);    //  98.3 MB
    float*  gh    = (float*) alloc((size_t)B_ * G3_ * 4);     //  19.7 MB
    float*  h     = (float*) alloc((size_t)B_ * H_ * 4);      //   6.6 MB
    bf16_t* hb    = (bf16_t*)alloc((size_t)B_ * H_ * 2);      //   3.3 MB
    bf16_t* yb    = (bf16_t*)alloc((size_t)B_ * MIN_ * 2);    //  16.4 MB
    bf16_t* t1b   = (bf16_t*)alloc((size_t)B_ * MH_ * 2);     //   5.2 MB

    // h0 = 0 (fp32 and bf16 views)
    hipMemsetAsync(h,  0, (size_t)B_ * H_ * sizeof(float), stream);
    hipMemsetAsync(hb, 0, (size_t)B_ * H_ * sizeof(bf16_t), stream);

    // weight converts
    {
        int n = G3_ * SEQ_;
        f2bf_kernel<<<(n / 4 + 255) / 256, 256, 0, stream>>>(w_ih, wihb, n);
    }
    {
        int n = G3_ * H_;
        f2bf_kernel<<<(n / 4 + 255) / 256, 256, 0, stream>>>(w_hh, whhb, n);
    }
    {   // w1 [MIN, MH] -> w1t [MH, MIN]
        dim3 grid((MH_ + 31) / 32, (MIN_ + 31) / 32);
        tconv_kernel<<<grid, 256, 0, stream>>>(w1, w1t, MIN_, MH_);
    }
    {   // w2 [MH, MO] -> w2t [MO, MH]
        dim3 grid((MO_ + 31) / 32, (MH_ + 31) / 32);
        tconv_kernel<<<grid, 256, 0, stream>>>(w2, w2t, MH_, MO_);
    }

    // GNN over all graphs -> seq (bf16); one wave per graph, 4 graphs/block
    gnn_kernel<<<BS_ / 4, 256, 0, stream>>>(x, ei, ef, ea, Wx, We, Wf, Wedge, seq);

    // gi = seq @ w_ih^T + b_ih  (all timesteps at once)
    // M=10240 (80 tiles of 128), N=2400 (19 tiles), K=5376 (84 K-tiles of 64)
    {
        int nblocks = (BS_ / 128) * ((G3_ + 127) / 128);   // 80*19 = 1520
        gemm2ph<64, float><<<nblocks, 256, 0, stream>>>(seq, wihb, b_ih, gi, BS_, G3_, SEQ_);
    }

    // GRU steps: gh = h @ w_hh^T + b_hh, then fused gates
    for (int t = 0; t < S_; t++) {
        int nblocks = (B_ / 128) * ((G3_ + 127) / 128);    // 16*19 = 304
        gemm2ph<32, float><<<nblocks, 256, 0, stream>>>(hb, whhb, b_hh, gh, B_, G3_, H_);
        gru_gates_kernel<<<(B_ * H_ + 255) / 256, 256, 0, stream>>>(gi, gh, h, hb, yb, t);
    }

    // MLP: t1 = y @ w1 + b1 (bf16 out) ; out = t1 @ w2 + b2 (fp32 out)
    {
        int nblocks = (B_ / 128) * ((MH_ + 127) / 128);    // 16*10 = 160
        gemm2ph<32, bf16_t><<<nblocks, 256, 0, stream>>>(yb, w1t, b1, t1b, B_, MH_, MIN_);
    }
    {
        int nblocks = (B_ / 128) * ((MO_ + 127) / 128);    // 16*4 = 64
        gemm2ph<32, float><<<nblocks, 256, 0, stream>>>(t1b, w2t, b2, out, B_, MO_, MH_);
    }
}